// Round 12
// baseline (528.633 us; speedup 1.0000x reference)
//
#include <hip/hip_runtime.h>
#include <math.h>

#define NNODES 50000
#define NEDGES 600000
#define HIDDIM 128
#define NHEAD 8
#define DM 64
#define NCLS 40
// packed feature row: [q 128 | k 128 | v 128 | m 64 | hg 8 | h 128]
#define FSTR 584
#define OFF_K 128
#define OFF_V 256
#define OFF_M 384
#define OFF_HG 448
#define OFF_H 456
#define NBLK 196            // ceil(NNODES/256)
#define CONV_TOTAL (NNODES * HIDDIM / 2)   // 3.2M bf16 pairs

typedef __attribute__((ext_vector_type(8))) short short8;
typedef __attribute__((ext_vector_type(4))) float f32x4;

static __device__ __forceinline__ unsigned short f2bf(float f) {
    unsigned u = __float_as_uint(f);
    unsigned r = (u + 0x7fffu + ((u >> 16) & 1u)) >> 16;
    return (unsigned short)r;
}
static __device__ __forceinline__ float bflo(unsigned u) { return __uint_as_float(u << 16); }
static __device__ __forceinline__ float bfhi(unsigned u) { return __uint_as_float(u & 0xffff0000u); }
static __device__ __forceinline__ float bf2f(unsigned short s) {
    return __uint_as_float(((unsigned)s) << 16);
}

// ---------------- bf16 MFMA GEMM, one A-pass, BM=64 ------------------------
// C = act( [A1|A2] @ B ), B pre-transposed bf16 BT[NN][K].
// Block = 4 waves, each wave 16 rows (1 m-frag); grid (1, ceil(M/64)) = 782
// blocks (~3/CU) for latency hiding. A loaded ONCE into registers, then loop
// over ceil(NN/64) column tiles re-reading only B (L2-resident).
// Frags (16x16x32 bf16): A row=l&15,k=8*(l>>4)+j ; D col=l&15,row=4*(l>>4)+reg.
template <int KCHUNKS, int ACT>
__global__ __launch_bounds__(256) void gemm_1p(
    const unsigned short* __restrict__ A1, int lda1, int K1,
    const unsigned short* __restrict__ A2, int lda2, int K2,
    const unsigned short* __restrict__ BT,
    unsigned short* __restrict__ Cb1, int ldb1, int off1,
    int M, int NN)
{
    const int K = KCHUNKS * 32;
    const int l = threadIdx.x & 63, wv = threadIdx.x >> 6;
    const int r = l & 15, g = l >> 4;
    const int row0 = blockIdx.y * 64 + wv * 16;
    const int arow = row0 + r;

    short8 a[KCHUNKS];
#pragma unroll
    for (int kc = 0; kc < KCHUNKS; ++kc) {
        int kg = kc * 32;
        const unsigned short* Ak;
        int ka, lda;
        if (kg < K1) { Ak = A1; ka = kg; lda = lda1; }
        else         { Ak = A2; ka = kg - K1; lda = lda2; }
        if (arow < M)
            a[kc] = *reinterpret_cast<const short8*>(Ak + (size_t)arow * lda + ka + 8 * g);
        else
            a[kc] = short8{0, 0, 0, 0, 0, 0, 0, 0};
    }

    const int ntiles = (NN + 63) >> 6;
    for (int t = 0; t < ntiles; ++t) {
        const int col0 = t * 64;
        f32x4 acc[4] = {};
#pragma unroll
        for (int kc = 0; kc < KCHUNKS; ++kc) {
            short8 b[4];
#pragma unroll
            for (int n = 0; n < 4; ++n) {
                int col = col0 + n * 16 + r;
                if (col < NN)
                    b[n] = *reinterpret_cast<const short8*>(BT + (size_t)col * K + kc * 32 + 8 * g);
                else
                    b[n] = short8{0, 0, 0, 0, 0, 0, 0, 0};
            }
#pragma unroll
            for (int n = 0; n < 4; ++n)
                acc[n] = __builtin_amdgcn_mfma_f32_16x16x32_bf16(a[kc], b[n], acc[n], 0, 0, 0);
        }
#pragma unroll
        for (int j = 0; j < 4; ++j) {
            int row = row0 + 4 * g + j;
            if (row >= M) continue;
#pragma unroll
            for (int n = 0; n < 4; ++n) {
                int col = col0 + n * 16 + r;
                if (col >= NN) continue;
                float vv = acc[n][j];
                if (ACT) vv = vv > 0.f ? vv : 0.1f * vv;
                Cb1[(size_t)row * ldb1 + off1 + col] = f2bf(vv);
            }
        }
    }
}

// ---------------- classifier GEMM + fused log-softmax ----------------------
// out[M,40] = log_softmax(A @ BTout), BTout 64x128 (cols 40..63 zero-padded).
// Row-softmax in-register: rows live in 16-lane groups (D col = l&15).
__global__ __launch_bounds__(256) void gemm_cls_lsm(
    const unsigned short* __restrict__ A, int lda,
    const unsigned short* __restrict__ BT,
    float* __restrict__ out, int M)
{
    const int l = threadIdx.x & 63, wv = threadIdx.x >> 6;
    const int r = l & 15, g = l >> 4;
    const int row0 = blockIdx.y * 64 + wv * 16;
    const int arow = row0 + r;

    short8 a[4];
#pragma unroll
    for (int kc = 0; kc < 4; ++kc) {
        if (arow < M)
            a[kc] = *reinterpret_cast<const short8*>(A + (size_t)arow * lda + kc * 32 + 8 * g);
        else
            a[kc] = short8{0, 0, 0, 0, 0, 0, 0, 0};
    }
    f32x4 acc[4] = {};
#pragma unroll
    for (int kc = 0; kc < 4; ++kc) {
        short8 b[4];
#pragma unroll
        for (int n = 0; n < 4; ++n) {
            int col = n * 16 + r;   // 0..63, BT has 64 rows
            b[n] = *reinterpret_cast<const short8*>(BT + (size_t)col * 128 + kc * 32 + 8 * g);
        }
#pragma unroll
        for (int n = 0; n < 4; ++n)
            acc[n] = __builtin_amdgcn_mfma_f32_16x16x32_bf16(a[kc], b[n], acc[n], 0, 0, 0);
    }
#pragma unroll
    for (int j = 0; j < 4; ++j) {
        int row = row0 + 4 * g + j;
        float mx = -INFINITY;
#pragma unroll
        for (int n = 0; n < 4; ++n) {
            int col = n * 16 + r;
            if (col < NCLS) mx = fmaxf(mx, acc[n][j]);
        }
        mx = fmaxf(mx, __shfl_xor(mx, 1));
        mx = fmaxf(mx, __shfl_xor(mx, 2));
        mx = fmaxf(mx, __shfl_xor(mx, 4));
        mx = fmaxf(mx, __shfl_xor(mx, 8));
        float sm = 0.f;
#pragma unroll
        for (int n = 0; n < 4; ++n) {
            int col = n * 16 + r;
            if (col < NCLS) sm += __expf(acc[n][j] - mx);
        }
        sm += __shfl_xor(sm, 1);
        sm += __shfl_xor(sm, 2);
        sm += __shfl_xor(sm, 4);
        sm += __shfl_xor(sm, 8);
        float lse = mx + logf(sm);
        if (row < M) {
#pragma unroll
            for (int n = 0; n < 4; ++n) {
                int col = n * 16 + r;
                if (col < NCLS) out[(size_t)row * NCLS + col] = acc[n][j] - lse;
            }
        }
    }
}

// ---------------- fused prep: weight pack + x->bf16 + degree hist ----------
//   BTin    @ 0       : 128x128
//   BTqkvm0 @ 16384   : 456x128   (out cols: q|k|v|m|hg)
//   BTqkvm1 @ 74752   : 456x128
//   BTo0    @ 133120  : 128x256
//   BTo1    @ 165888  : 128x256
//   BTout   @ 198656  : 64x128    (cols 40..63 zero-padded)
#define BT_TOTAL 206848
__global__ __launch_bounds__(256) void prep_kernel(
    const float* __restrict__ x, const int* __restrict__ ei,
    const float* __restrict__ w_in, const float* __restrict__ w_out,
    const float* __restrict__ Wq, const float* __restrict__ Wk,
    const float* __restrict__ Wv, const float* __restrict__ Wm,
    const float* __restrict__ Wg, const float* __restrict__ Wo,
    unsigned short* __restrict__ BT, unsigned int* __restrict__ xb2,
    int* __restrict__ degi)
{
    int i = blockIdx.x * 256 + threadIdx.x;
    if (i < CONV_TOTAL) {
        float2 f = *reinterpret_cast<const float2*>(x + (size_t)i * 2);
        xb2[i] = (unsigned)f2bf(f.x) | ((unsigned)f2bf(f.y) << 16);
    }
    if (i < NEDGES) {
        unsigned d = (unsigned)ei[NEDGES + i]; if (d >= NNODES) d = 0;
        atomicAdd(&degi[d], 1);
    }
    if (i < BT_TOTAL) {
        float val;
        if (i < 16384) {
            int c = i >> 7, k = i & 127;
            val = w_in[k * 128 + c];
        } else if (i < 133120) {
            int li = i - 16384;
            int L = li / 58368, t = li % 58368;
            int c = t >> 7, k = t & 127;
            if      (c < 128) val = Wq[L * 16384 + k * 128 + c];
            else if (c < 256) val = Wk[L * 16384 + k * 128 + (c - 128)];
            else if (c < 384) val = Wv[L * 16384 + k * 128 + (c - 256)];
            else if (c < 448) val = Wm[L * 8192  + k * 64  + (c - 384)];
            else              val = Wg[L * 2560 + (192 + k) * 8 + (c - 448)]; // hg = h @ Wg_mean
        } else if (i < 198656) {
            int li = i - 133120;
            int L = li / 32768, t = li % 32768;
            int c = t >> 8, k = t & 255;
            val = Wo[L * 32768 + k * 128 + c];
        } else {
            int t = i - 198656;
            int c = t >> 7, k = t & 127;
            val = (c < NCLS) ? w_out[k * NCLS + c] : 0.f;
        }
        BT[i] = f2bf(val);
    }
}

// ---------------- CSR scan + scatter ---------------------------------------
static __device__ __forceinline__ int wave_incl_scan(int x, int lane) {
#pragma unroll
    for (int off = 1; off < 64; off <<= 1) {
        int n = __shfl_up(x, off);
        if (lane >= off) x += n;
    }
    return x;
}

__global__ __launch_bounds__(256) void scan_blk_kernel(
    const int* __restrict__ degi, int* __restrict__ rowptr,
    int* __restrict__ bsum)
{
    __shared__ int wsum[4];
    const int t = threadIdx.x, b = blockIdx.x;
    const int idx = b * 256 + t;
    const int lane = t & 63, wv = t >> 6;
    int v = (idx < NNODES) ? degi[idx] : 0;
    int incl = wave_incl_scan(v, lane);
    if (lane == 63) wsum[wv] = incl;
    __syncthreads();
    int wpre = 0;
#pragma unroll
    for (int w = 0; w < 4; ++w) wpre += (w < wv) ? wsum[w] : 0;
    if (idx < NNODES) rowptr[idx] = wpre + incl - v;
    if (t == 255) bsum[b] = wpre + incl;
}

__global__ __launch_bounds__(256) void scan_top_kernel(
    const int* __restrict__ bsum, int* __restrict__ boff,
    int* __restrict__ rowptr)
{
    __shared__ int wsum[4];
    const int t = threadIdx.x;
    const int lane = t & 63, wv = t >> 6;
    int v = (t < NBLK) ? bsum[t] : 0;
    int incl = wave_incl_scan(v, lane);
    if (lane == 63) wsum[wv] = incl;
    __syncthreads();
    int wpre = 0;
#pragma unroll
    for (int w = 0; w < 4; ++w) wpre += (w < wv) ? wsum[w] : 0;
    if (t < NBLK) boff[t] = wpre + incl - v;
    if (t == 0) rowptr[NNODES] = NEDGES;
}

__global__ __launch_bounds__(256) void scan_add_kernel(
    int* __restrict__ rowptr, const int* __restrict__ boff)
{
    int idx = blockIdx.x * 256 + threadIdx.x;
    if (idx < NNODES) rowptr[idx] += boff[blockIdx.x];
}

__global__ __launch_bounds__(256) void scatter_kernel(
    const int* __restrict__ ei, const int* __restrict__ rowptr,
    int* __restrict__ fill, int* __restrict__ csr_src)
{
    int e = blockIdx.x * 256 + threadIdx.x;
    if (e >= NEDGES) return;
    unsigned s = (unsigned)ei[e];          if (s >= NNODES) s = 0;
    unsigned d = (unsigned)ei[NEDGES + e]; if (d >= NNODES) d = 0;
    int pos = rowptr[d] + atomicAdd(&fill[d], 1);
    csr_src[pos] = (int)s;
}

// ---------------- fused edge phase + gate + gated --------------------------
// one wave per dst node; lane l owns cols 2l,2l+1 (head = l>>3).
// feat: bf16 [N][584] = [q|k|v|m|hg|h]. Writes ONLY gatedb [N][128] bf16.
// Defer-max (T13): rescale only when pmax > mr + 8 (exact math, P <= e^8).
__global__ __launch_bounds__(256) void fused_edge_kernel(
    const int* __restrict__ rowptr, const int* __restrict__ csr_src,
    const unsigned short* __restrict__ feat, const float* __restrict__ Wg,
    unsigned short* __restrict__ gatedb)
{
    int node = blockIdx.x * 4 + (threadIdx.x >> 6);
    if (node >= NNODES) return;
    const int lane = threadIdx.x & 63;
    const int c2 = lane * 2;
    const int j0 = lane & 7;

    const int start = rowptr[node], end = rowptr[node + 1];
    const int deg = end - start;

    const unsigned short* frow = feat + (size_t)node * FSTR;
    unsigned qu = *reinterpret_cast<const unsigned*>(frow + c2);
    float qx = bflo(qu), qy = bfhi(qu);

    float mr = -INFINITY, dr = 0.f;
    float a0 = 0.f, a1 = 0.f;
    float hgs = 0.f;               // meanpool projection component j0
    float mm = -INFINITY;

    int p = start;
    for (; p + 2 <= end; p += 2) {
        int s0 = csr_src[p], s1 = csr_src[p + 1];
        const unsigned short* r0 = feat + (size_t)s0 * FSTR;
        const unsigned short* r1 = feat + (size_t)s1 * FSTR;
        unsigned ku0 = *reinterpret_cast<const unsigned*>(r0 + OFF_K + c2);
        unsigned vu0 = *reinterpret_cast<const unsigned*>(r0 + OFF_V + c2);
        float    mv0 = bf2f(r0[OFF_M + lane]);
        float    hg0 = bf2f(r0[OFF_HG + j0]);
        unsigned ku1 = *reinterpret_cast<const unsigned*>(r1 + OFF_K + c2);
        unsigned vu1 = *reinterpret_cast<const unsigned*>(r1 + OFF_V + c2);
        float    mv1 = bf2f(r1[OFF_M + lane]);
        float    hg1 = bf2f(r1[OFF_HG + j0]);

        float sc0 = qx * bflo(ku0) + qy * bfhi(ku0);
        float sc1 = qx * bflo(ku1) + qy * bfhi(ku1);
        sc0 += __shfl_xor(sc0, 1);  sc1 += __shfl_xor(sc1, 1);
        sc0 += __shfl_xor(sc0, 2);  sc1 += __shfl_xor(sc1, 2);
        sc0 += __shfl_xor(sc0, 4);  sc1 += __shfl_xor(sc1, 4);

        float pm = fmaxf(sc0, sc1);
        if (pm > mr + 8.f) {       // defer-max: rare after warm-up
            float scale = __expf(mr - pm);   // mr=-inf -> 0, harmless
            dr *= scale; a0 *= scale; a1 *= scale;
            mr = pm;
        }
        float e0 = __expf(sc0 - mr), e1 = __expf(sc1 - mr);
        dr += e0 + e1;
        a0 = fmaf(e0, bflo(vu0), a0); a0 = fmaf(e1, bflo(vu1), a0);
        a1 = fmaf(e0, bfhi(vu0), a1); a1 = fmaf(e1, bfhi(vu1), a1);

        hgs += hg0 + hg1;
        mm = fmaxf(mm, fmaxf(mv0, mv1));
    }
    if (p < end) {
        int s0 = csr_src[p];
        const unsigned short* r0 = feat + (size_t)s0 * FSTR;
        unsigned ku0 = *reinterpret_cast<const unsigned*>(r0 + OFF_K + c2);
        unsigned vu0 = *reinterpret_cast<const unsigned*>(r0 + OFF_V + c2);
        float    mv0 = bf2f(r0[OFF_M + lane]);
        float    hg0 = bf2f(r0[OFF_HG + j0]);

        float sc0 = qx * bflo(ku0) + qy * bfhi(ku0);
        sc0 += __shfl_xor(sc0, 1);
        sc0 += __shfl_xor(sc0, 2);
        sc0 += __shfl_xor(sc0, 4);

        if (sc0 > mr + 8.f) {
            float scale = __expf(mr - sc0);
            dr *= scale; a0 *= scale; a1 *= scale;
            mr = sc0;
        }
        float e0 = __expf(sc0 - mr);
        dr += e0;
        a0 = fmaf(e0, bflo(vu0), a0);
        a1 = fmaf(e0, bfhi(vu0), a1);

        hgs += hg0;
        mm = fmaxf(mm, mv0);
    }

    float inv  = 1.f / (dr + 1e-16f);
    float invd = 1.f / fmaxf((float)deg, 1.f);
    if (deg == 0) { mm = 0.f; inv = 0.f; }

    // ---- gate: g = sigmoid([h_i, maxpool, meanpool] @ Wg), fused in-wave --
    unsigned hou = *reinterpret_cast<const unsigned*>(frow + OFF_H + c2);
    float hx = bflo(hou), hy = bfhi(hou);

    const float* w0 = Wg + (size_t)c2 * 8;            // h row 2l
    const float* w1 = Wg + (size_t)(c2 + 1) * 8;      // h row 2l+1
    const float* w2 = Wg + (size_t)(128 + lane) * 8;  // maxpool row l

    float part[8];
#pragma unroll
    for (int j = 0; j < 8; ++j)
        part[j] = hx * w0[j] + hy * w1[j] + mm * w2[j];
#pragma unroll
    for (int off = 1; off < 64; off <<= 1)
#pragma unroll
        for (int j = 0; j < 8; ++j)
            part[j] += __shfl_xor(part[j], off);

    float mc = __shfl(hgs, lane >> 3);   // meanpool@Wgm component (lane>>3)
    float gg = 1.f / (1.f + __expf(-(part[lane >> 3] + mc * invd)));
    float o0 = gg * a0 * inv, o1 = gg * a1 * inv;
    unsigned outu = (unsigned)f2bf(o0) | ((unsigned)f2bf(o1) << 16);
    *reinterpret_cast<unsigned*>(gatedb + (size_t)node * HIDDIM + c2) = outu;
}

// ---------------- host ----------------------------------------------------
static inline int cdiv(int a, int b) { return (a + b - 1) / b; }

extern "C" void kernel_launch(void* const* d_in, const int* in_sizes, int n_in,
                              void* d_out, int out_size, void* d_ws, size_t ws_size,
                              hipStream_t stream)
{
    const float* x     = (const float*)d_in[0];
    const int*   ei    = (const int*)d_in[1];
    const float* w_in  = (const float*)d_in[2];
    const float* w_out = (const float*)d_in[3];
    const float* Wq    = (const float*)d_in[4];
    const float* Wk    = (const float*)d_in[5];
    const float* Wv    = (const float*)d_in[6];
    const float* Wm    = (const float*)d_in[7];
    const float* Wg    = (const float*)d_in[8];
    const float* Wo    = (const float*)d_in[9];
    float* out = (float*)d_out;

    const size_t NF = NNODES;
    unsigned short* xb     = (unsigned short*)d_ws;           // N*128
    unsigned short* feat0  = xb    + NF * 128;                // N*584
    unsigned short* feat1  = feat0 + NF * FSTR;               // N*584
    unsigned short* gatedb = feat1 + NF * FSTR;               // N*128
    unsigned short* BTpool = gatedb + NF * 128;               // 206848
    int* rowptr  = (int*)(BTpool + BT_TOTAL);                 // N+1
    int* degi    = rowptr + (NNODES + 1);                     // N
    int* fill    = degi + NNODES;                             // N
    int* csr_src = fill + NNODES;                             // E
    int* bsum    = csr_src + NEDGES;                          // NBLK
    int* boff    = bsum + NBLK;                               // NBLK

    const unsigned short* BTin    = BTpool;
    const unsigned short* BTqkvm0 = BTpool + 16384;
    const unsigned short* BTqkvm1 = BTpool + 74752;
    const unsigned short* BTo0    = BTpool + 133120;
    const unsigned short* BTo1    = BTpool + 165888;
    const unsigned short* BTout   = BTpool + 198656;

    // ---- prep: memset, then fused pack+convert+hist, then scan+scatter ----
    hipMemsetAsync(degi, 0, 2 * NNODES * sizeof(int), stream);  // degi + fill
    prep_kernel<<<cdiv(CONV_TOTAL, 256), 256, 0, stream>>>(
        x, ei, w_in, w_out, Wq, Wk, Wv, Wm, Wg, Wo,
        BTpool, (unsigned int*)xb, degi);
    scan_blk_kernel<<<NBLK, 256, 0, stream>>>(degi, rowptr, bsum);
    scan_top_kernel<<<1, 256, 0, stream>>>(bsum, boff, rowptr);
    scan_add_kernel<<<NBLK, 256, 0, stream>>>(rowptr, boff);
    scatter_kernel<<<cdiv(NEDGES, 256), 256, 0, stream>>>(ei, rowptr, fill, csr_src);

    const dim3 gM(1, cdiv(NNODES, 64));   // 782 blocks, ~3/CU

    // h0 = x @ w_in  -> feat0[.,456..583]
    gemm_1p<4, 0><<<gM, 256, 0, stream>>>(
        xb, 128, 128, nullptr, 0, 0, BTin,
        feat0, FSTR, OFF_H, NNODES, 128);

    unsigned short* featA = feat0;
    unsigned short* featB = feat1;
    for (int L = 0; L < 2; ++L) {
        const unsigned short* btq = L ? BTqkvm1 : BTqkvm0;
        const unsigned short* bto = L ? BTo1 : BTo0;
        const float* wg = Wg + (size_t)L * 320 * 8;

        // [q|k|v|m|hg] = h @ [wq|wk|wv|wm|wgm]  -> feat[.,0..455]
        gemm_1p<4, 0><<<gM, 256, 0, stream>>>(
            featA + OFF_H, FSTR, 128, nullptr, 0, 0, btq,
            featA, FSTR, 0, NNODES, 456);

        fused_edge_kernel<<<cdiv(NNODES, 4), 256, 0, stream>>>(
            rowptr, csr_src, featA, wg, gatedb);

        // h' = leaky_relu([h | gated] @ wo) -> featB[.,456..583]
        gemm_1p<8, 1><<<gM, 256, 0, stream>>>(
            featA + OFF_H, FSTR, 128, gatedb, 128, 128, bto,
            featB, FSTR, OFF_H, NNODES, 128);

        unsigned short* t = featA; featA = featB; featB = t;
    }

    // classifier + fused log-softmax (featA holds final hidden state)
    gemm_cls_lsm<<<gM, 256, 0, stream>>>(
        featA + OFF_H, FSTR, BTout, out, NNODES);
}

// Round 13
// 453.458 us; speedup vs baseline: 1.1658x; 1.1658x over previous
//
#include <hip/hip_runtime.h>
#include <math.h>

#define NNODES 50000
#define NEDGES 600000
#define HIDDIM 128
#define NHEAD 8
#define DM 64
#define NCLS 40
// packed feature row: [q 128 | k 128 | v 128 | m 64 | hg 8 | h 128]
#define FSTR 584
#define OFF_K 128
#define OFF_V 256
#define OFF_M 384
#define OFF_HG 448
#define OFF_H 456
#define NBLK 196            // ceil(NNODES/256)
#define CONV_TOTAL (NNODES * HIDDIM / 2)   // 3.2M bf16 pairs

typedef __attribute__((ext_vector_type(8))) short short8;
typedef __attribute__((ext_vector_type(4))) float f32x4;

static __device__ __forceinline__ unsigned short f2bf(float f) {
    unsigned u = __float_as_uint(f);
    unsigned r = (u + 0x7fffu + ((u >> 16) & 1u)) >> 16;
    return (unsigned short)r;
}
static __device__ __forceinline__ float bflo(unsigned u) { return __uint_as_float(u << 16); }
static __device__ __forceinline__ float bfhi(unsigned u) { return __uint_as_float(u & 0xffff0000u); }
static __device__ __forceinline__ float bf2f(unsigned short s) {
    return __uint_as_float(((unsigned)s) << 16);
}

// ---------------- bf16 MFMA GEMM, one A-pass, BM=128 (round-11 best) -------
// C = act( [A1|A2] @ B ), B pre-transposed bf16 BT[NN][K].
// Block = 4 waves, 32 rows/wave (2 m-frags); grid (1, ceil(M/128)) = 391.
// A loaded ONCE into registers (KCHUNKS*2 short8/lane); loop over ceil(NN/64)
// column tiles re-reading only B (L2-resident). BM=64 measured WORSE (r12:
// +63us — halves MFMA per B-load and doubles B re-reads); BM=256/BN=128
// measured worse (r10). Keep BM=128.
// Frags (16x16x32 bf16): A row=l&15,k=8*(l>>4)+j ; D col=l&15,row=4*(l>>4)+reg.
template <int KCHUNKS, int ACT>
__global__ __launch_bounds__(256) void gemm_1p(
    const unsigned short* __restrict__ A1, int lda1, int K1,
    const unsigned short* __restrict__ A2, int lda2, int K2,
    const unsigned short* __restrict__ BT,
    unsigned short* __restrict__ Cb1, int ldb1, int off1,
    int M, int NN)
{
    const int K = KCHUNKS * 32;
    const int l = threadIdx.x & 63, wv = threadIdx.x >> 6;
    const int r = l & 15, g = l >> 4;
    const int row0 = blockIdx.y * 128 + wv * 32;

    short8 a[KCHUNKS][2];
#pragma unroll
    for (int kc = 0; kc < KCHUNKS; ++kc) {
        int kg = kc * 32;
        const unsigned short* Ak;
        int ka, lda;
        if (kg < K1) { Ak = A1; ka = kg; lda = lda1; }
        else         { Ak = A2; ka = kg - K1; lda = lda2; }
#pragma unroll
        for (int m = 0; m < 2; ++m) {
            int row = row0 + m * 16 + r;
            if (row < M)
                a[kc][m] = *reinterpret_cast<const short8*>(Ak + (size_t)row * lda + ka + 8 * g);
            else
                a[kc][m] = short8{0, 0, 0, 0, 0, 0, 0, 0};
        }
    }

    const int ntiles = (NN + 63) >> 6;
    for (int t = 0; t < ntiles; ++t) {
        const int col0 = t * 64;
        f32x4 acc[2][4] = {};
#pragma unroll
        for (int kc = 0; kc < KCHUNKS; ++kc) {
            short8 b[4];
#pragma unroll
            for (int n = 0; n < 4; ++n) {
                int col = col0 + n * 16 + r;
                if (col < NN)
                    b[n] = *reinterpret_cast<const short8*>(BT + (size_t)col * K + kc * 32 + 8 * g);
                else
                    b[n] = short8{0, 0, 0, 0, 0, 0, 0, 0};
            }
#pragma unroll
            for (int m = 0; m < 2; ++m)
#pragma unroll
                for (int n = 0; n < 4; ++n)
                    acc[m][n] = __builtin_amdgcn_mfma_f32_16x16x32_bf16(a[kc][m], b[n], acc[m][n], 0, 0, 0);
        }
#pragma unroll
        for (int m = 0; m < 2; ++m) {
#pragma unroll
            for (int j = 0; j < 4; ++j) {
                int row = row0 + m * 16 + 4 * g + j;
                if (row >= M) continue;
#pragma unroll
                for (int n = 0; n < 4; ++n) {
                    int col = col0 + n * 16 + r;
                    if (col >= NN) continue;
                    float vv = acc[m][n][j];
                    if (ACT) vv = vv > 0.f ? vv : 0.1f * vv;
                    Cb1[(size_t)row * ldb1 + off1 + col] = f2bf(vv);
                }
            }
        }
    }
}

// ---------------- classifier GEMM + fused log-softmax (BM=128) -------------
// out[M,40] = log_softmax(A @ BTout), BTout 64x128 (cols 40..63 zero-padded).
// Row-softmax in-register: rows live in 16-lane groups (D col = l&15).
__global__ __launch_bounds__(256) void gemm_cls_lsm(
    const unsigned short* __restrict__ A, int lda,
    const unsigned short* __restrict__ BT,
    float* __restrict__ out, int M)
{
    const int l = threadIdx.x & 63, wv = threadIdx.x >> 6;
    const int r = l & 15, g = l >> 4;
    const int row0 = blockIdx.y * 128 + wv * 32;

    short8 a[4][2];
#pragma unroll
    for (int kc = 0; kc < 4; ++kc) {
#pragma unroll
        for (int m = 0; m < 2; ++m) {
            int row = row0 + m * 16 + r;
            if (row < M)
                a[kc][m] = *reinterpret_cast<const short8*>(A + (size_t)row * lda + kc * 32 + 8 * g);
            else
                a[kc][m] = short8{0, 0, 0, 0, 0, 0, 0, 0};
        }
    }
    f32x4 acc[2][4] = {};
#pragma unroll
    for (int kc = 0; kc < 4; ++kc) {
        short8 b[4];
#pragma unroll
        for (int n = 0; n < 4; ++n) {
            int col = n * 16 + r;   // 0..63, BT has 64 rows
            b[n] = *reinterpret_cast<const short8*>(BT + (size_t)col * 128 + kc * 32 + 8 * g);
        }
#pragma unroll
        for (int m = 0; m < 2; ++m)
#pragma unroll
            for (int n = 0; n < 4; ++n)
                acc[m][n] = __builtin_amdgcn_mfma_f32_16x16x32_bf16(a[kc][m], b[n], acc[m][n], 0, 0, 0);
    }
#pragma unroll
    for (int m = 0; m < 2; ++m) {
#pragma unroll
        for (int j = 0; j < 4; ++j) {
            int row = row0 + m * 16 + 4 * g + j;
            float mx = -INFINITY;
#pragma unroll
            for (int n = 0; n < 4; ++n) {
                int col = n * 16 + r;
                if (col < NCLS) mx = fmaxf(mx, acc[m][n][j]);
            }
            mx = fmaxf(mx, __shfl_xor(mx, 1));
            mx = fmaxf(mx, __shfl_xor(mx, 2));
            mx = fmaxf(mx, __shfl_xor(mx, 4));
            mx = fmaxf(mx, __shfl_xor(mx, 8));
            float sm = 0.f;
#pragma unroll
            for (int n = 0; n < 4; ++n) {
                int col = n * 16 + r;
                if (col < NCLS) sm += __expf(acc[m][n][j] - mx);
            }
            sm += __shfl_xor(sm, 1);
            sm += __shfl_xor(sm, 2);
            sm += __shfl_xor(sm, 4);
            sm += __shfl_xor(sm, 8);
            float lse = mx + logf(sm);
            if (row < M) {
#pragma unroll
                for (int n = 0; n < 4; ++n) {
                    int col = n * 16 + r;
                    if (col < NCLS) out[(size_t)row * NCLS + col] = acc[m][n][j] - lse;
                }
            }
        }
    }
}

// ---------------- fused prep: weight pack + x->bf16 + degree hist ----------
//   BTin    @ 0       : 128x128
//   BTqkvm0 @ 16384   : 456x128   (out cols: q|k|v|m|hg)
//   BTqkvm1 @ 74752   : 456x128
//   BTo0    @ 133120  : 128x256
//   BTo1    @ 165888  : 128x256
//   BTout   @ 198656  : 64x128    (cols 40..63 zero-padded)
#define BT_TOTAL 206848
__global__ __launch_bounds__(256) void prep_kernel(
    const float* __restrict__ x, const int* __restrict__ ei,
    const float* __restrict__ w_in, const float* __restrict__ w_out,
    const float* __restrict__ Wq, const float* __restrict__ Wk,
    const float* __restrict__ Wv, const float* __restrict__ Wm,
    const float* __restrict__ Wg, const float* __restrict__ Wo,
    unsigned short* __restrict__ BT, unsigned int* __restrict__ xb2,
    int* __restrict__ degi)
{
    int i = blockIdx.x * 256 + threadIdx.x;
    if (i < CONV_TOTAL) {
        float2 f = *reinterpret_cast<const float2*>(x + (size_t)i * 2);
        xb2[i] = (unsigned)f2bf(f.x) | ((unsigned)f2bf(f.y) << 16);
    }
    if (i < NEDGES) {
        unsigned d = (unsigned)ei[NEDGES + i]; if (d >= NNODES) d = 0;
        atomicAdd(&degi[d], 1);
    }
    if (i < BT_TOTAL) {
        float val;
        if (i < 16384) {
            int c = i >> 7, k = i & 127;
            val = w_in[k * 128 + c];
        } else if (i < 133120) {
            int li = i - 16384;
            int L = li / 58368, t = li % 58368;
            int c = t >> 7, k = t & 127;
            if      (c < 128) val = Wq[L * 16384 + k * 128 + c];
            else if (c < 256) val = Wk[L * 16384 + k * 128 + (c - 128)];
            else if (c < 384) val = Wv[L * 16384 + k * 128 + (c - 256)];
            else if (c < 448) val = Wm[L * 8192  + k * 64  + (c - 384)];
            else              val = Wg[L * 2560 + (192 + k) * 8 + (c - 448)]; // hg = h @ Wg_mean
        } else if (i < 198656) {
            int li = i - 133120;
            int L = li / 32768, t = li % 32768;
            int c = t >> 8, k = t & 255;
            val = Wo[L * 32768 + k * 128 + c];
        } else {
            int t = i - 198656;
            int c = t >> 7, k = t & 127;
            val = (c < NCLS) ? w_out[k * NCLS + c] : 0.f;
        }
        BT[i] = f2bf(val);
    }
}

// ---------------- CSR scan + scatter ---------------------------------------
static __device__ __forceinline__ int wave_incl_scan(int x, int lane) {
#pragma unroll
    for (int off = 1; off < 64; off <<= 1) {
        int n = __shfl_up(x, off);
        if (lane >= off) x += n;
    }
    return x;
}

__global__ __launch_bounds__(256) void scan_blk_kernel(
    const int* __restrict__ degi, int* __restrict__ rowptr,
    int* __restrict__ bsum)
{
    __shared__ int wsum[4];
    const int t = threadIdx.x, b = blockIdx.x;
    const int idx = b * 256 + t;
    const int lane = t & 63, wv = t >> 6;
    int v = (idx < NNODES) ? degi[idx] : 0;
    int incl = wave_incl_scan(v, lane);
    if (lane == 63) wsum[wv] = incl;
    __syncthreads();
    int wpre = 0;
#pragma unroll
    for (int w = 0; w < 4; ++w) wpre += (w < wv) ? wsum[w] : 0;
    if (idx < NNODES) rowptr[idx] = wpre + incl - v;
    if (t == 255) bsum[b] = wpre + incl;
}

__global__ __launch_bounds__(256) void scan_top_kernel(
    const int* __restrict__ bsum, int* __restrict__ boff,
    int* __restrict__ rowptr)
{
    __shared__ int wsum[4];
    const int t = threadIdx.x;
    const int lane = t & 63, wv = t >> 6;
    int v = (t < NBLK) ? bsum[t] : 0;
    int incl = wave_incl_scan(v, lane);
    if (lane == 63) wsum[wv] = incl;
    __syncthreads();
    int wpre = 0;
#pragma unroll
    for (int w = 0; w < 4; ++w) wpre += (w < wv) ? wsum[w] : 0;
    if (t < NBLK) boff[t] = wpre + incl - v;
    if (t == 0) rowptr[NNODES] = NEDGES;
}

__global__ __launch_bounds__(256) void scan_add_kernel(
    int* __restrict__ rowptr, const int* __restrict__ boff)
{
    int idx = blockIdx.x * 256 + threadIdx.x;
    if (idx < NNODES) rowptr[idx] += boff[blockIdx.x];
}

__global__ __launch_bounds__(256) void scatter_kernel(
    const int* __restrict__ ei, const int* __restrict__ rowptr,
    int* __restrict__ fill, int* __restrict__ csr_src)
{
    int e = blockIdx.x * 256 + threadIdx.x;
    if (e >= NEDGES) return;
    unsigned s = (unsigned)ei[e];          if (s >= NNODES) s = 0;
    unsigned d = (unsigned)ei[NEDGES + e]; if (d >= NNODES) d = 0;
    int pos = rowptr[d] + atomicAdd(&fill[d], 1);
    csr_src[pos] = (int)s;
}

// ---------------- fused edge phase + gate + gated --------------------------
// one wave per dst node; lane l owns cols 2l,2l+1 (head = l>>3).
// feat: bf16 [N][584] = [q|k|v|m|hg|h]. Writes ONLY gatedb [N][128] bf16.
// Defer-max (T13): rescale only when pmax > mr + 8 (exact math, P <= e^8).
__global__ __launch_bounds__(256) void fused_edge_kernel(
    const int* __restrict__ rowptr, const int* __restrict__ csr_src,
    const unsigned short* __restrict__ feat, const float* __restrict__ Wg,
    unsigned short* __restrict__ gatedb)
{
    int node = blockIdx.x * 4 + (threadIdx.x >> 6);
    if (node >= NNODES) return;
    const int lane = threadIdx.x & 63;
    const int c2 = lane * 2;
    const int j0 = lane & 7;

    const int start = rowptr[node], end = rowptr[node + 1];
    const int deg = end - start;

    const unsigned short* frow = feat + (size_t)node * FSTR;
    unsigned qu = *reinterpret_cast<const unsigned*>(frow + c2);
    float qx = bflo(qu), qy = bfhi(qu);

    float mr = -INFINITY, dr = 0.f;
    float a0 = 0.f, a1 = 0.f;
    float hgs = 0.f;               // meanpool projection component j0
    float mm = -INFINITY;

    int p = start;
    for (; p + 2 <= end; p += 2) {
        int s0 = csr_src[p], s1 = csr_src[p + 1];
        const unsigned short* r0 = feat + (size_t)s0 * FSTR;
        const unsigned short* r1 = feat + (size_t)s1 * FSTR;
        unsigned ku0 = *reinterpret_cast<const unsigned*>(r0 + OFF_K + c2);
        unsigned vu0 = *reinterpret_cast<const unsigned*>(r0 + OFF_V + c2);
        float    mv0 = bf2f(r0[OFF_M + lane]);
        float    hg0 = bf2f(r0[OFF_HG + j0]);
        unsigned ku1 = *reinterpret_cast<const unsigned*>(r1 + OFF_K + c2);
        unsigned vu1 = *reinterpret_cast<const unsigned*>(r1 + OFF_V + c2);
        float    mv1 = bf2f(r1[OFF_M + lane]);
        float    hg1 = bf2f(r1[OFF_HG + j0]);

        float sc0 = qx * bflo(ku0) + qy * bfhi(ku0);
        float sc1 = qx * bflo(ku1) + qy * bfhi(ku1);
        sc0 += __shfl_xor(sc0, 1);  sc1 += __shfl_xor(sc1, 1);
        sc0 += __shfl_xor(sc0, 2);  sc1 += __shfl_xor(sc1, 2);
        sc0 += __shfl_xor(sc0, 4);  sc1 += __shfl_xor(sc1, 4);

        float pm = fmaxf(sc0, sc1);
        if (pm > mr + 8.f) {       // defer-max: rare after warm-up
            float scale = __expf(mr - pm);   // mr=-inf -> 0, harmless
            dr *= scale; a0 *= scale; a1 *= scale;
            mr = pm;
        }
        float e0 = __expf(sc0 - mr), e1 = __expf(sc1 - mr);
        dr += e0 + e1;
        a0 = fmaf(e0, bflo(vu0), a0); a0 = fmaf(e1, bflo(vu1), a0);
        a1 = fmaf(e0, bfhi(vu0), a1); a1 = fmaf(e1, bfhi(vu1), a1);

        hgs += hg0 + hg1;
        mm = fmaxf(mm, fmaxf(mv0, mv1));
    }
    if (p < end) {
        int s0 = csr_src[p];
        const unsigned short* r0 = feat + (size_t)s0 * FSTR;
        unsigned ku0 = *reinterpret_cast<const unsigned*>(r0 + OFF_K + c2);
        unsigned vu0 = *reinterpret_cast<const unsigned*>(r0 + OFF_V + c2);
        float    mv0 = bf2f(r0[OFF_M + lane]);
        float    hg0 = bf2f(r0[OFF_HG + j0]);

        float sc0 = qx * bflo(ku0) + qy * bfhi(ku0);
        sc0 += __shfl_xor(sc0, 1);
        sc0 += __shfl_xor(sc0, 2);
        sc0 += __shfl_xor(sc0, 4);

        if (sc0 > mr + 8.f) {
            float scale = __expf(mr - sc0);
            dr *= scale; a0 *= scale; a1 *= scale;
            mr = sc0;
        }
        float e0 = __expf(sc0 - mr);
        dr += e0;
        a0 = fmaf(e0, bflo(vu0), a0);
        a1 = fmaf(e0, bfhi(vu0), a1);

        hgs += hg0;
        mm = fmaxf(mm, mv0);
    }

    float inv  = 1.f / (dr + 1e-16f);
    float invd = 1.f / fmaxf((float)deg, 1.f);
    if (deg == 0) { mm = 0.f; inv = 0.f; }

    // ---- gate: g = sigmoid([h_i, maxpool, meanpool] @ Wg), fused in-wave --
    unsigned hou = *reinterpret_cast<const unsigned*>(frow + OFF_H + c2);
    float hx = bflo(hou), hy = bfhi(hou);

    const float* w0 = Wg + (size_t)c2 * 8;            // h row 2l
    const float* w1 = Wg + (size_t)(c2 + 1) * 8;      // h row 2l+1
    const float* w2 = Wg + (size_t)(128 + lane) * 8;  // maxpool row l

    float part[8];
#pragma unroll
    for (int j = 0; j < 8; ++j)
        part[j] = hx * w0[j] + hy * w1[j] + mm * w2[j];
#pragma unroll
    for (int off = 1; off < 64; off <<= 1)
#pragma unroll
        for (int j = 0; j < 8; ++j)
            part[j] += __shfl_xor(part[j], off);

    float mc = __shfl(hgs, lane >> 3);   // meanpool@Wgm component (lane>>3)
    float gg = 1.f / (1.f + __expf(-(part[lane >> 3] + mc * invd)));
    float o0 = gg * a0 * inv, o1 = gg * a1 * inv;
    unsigned outu = (unsigned)f2bf(o0) | ((unsigned)f2bf(o1) << 16);
    *reinterpret_cast<unsigned*>(gatedb + (size_t)node * HIDDIM + c2) = outu;
}

// ---------------- host ----------------------------------------------------
static inline int cdiv(int a, int b) { return (a + b - 1) / b; }

extern "C" void kernel_launch(void* const* d_in, const int* in_sizes, int n_in,
                              void* d_out, int out_size, void* d_ws, size_t ws_size,
                              hipStream_t stream)
{
    const float* x     = (const float*)d_in[0];
    const int*   ei    = (const int*)d_in[1];
    const float* w_in  = (const float*)d_in[2];
    const float* w_out = (const float*)d_in[3];
    const float* Wq    = (const float*)d_in[4];
    const float* Wk    = (const float*)d_in[5];
    const float* Wv    = (const float*)d_in[6];
    const float* Wm    = (const float*)d_in[7];
    const float* Wg    = (const float*)d_in[8];
    const float* Wo    = (const float*)d_in[9];
    float* out = (float*)d_out;

    const size_t NF = NNODES;
    unsigned short* xb     = (unsigned short*)d_ws;           // N*128
    unsigned short* feat0  = xb    + NF * 128;                // N*584
    unsigned short* feat1  = feat0 + NF * FSTR;               // N*584
    unsigned short* gatedb = feat1 + NF * FSTR;               // N*128
    unsigned short* BTpool = gatedb + NF * 128;               // 206848
    int* rowptr  = (int*)(BTpool + BT_TOTAL);                 // N+1
    int* degi    = rowptr + (NNODES + 1);                     // N
    int* fill    = degi + NNODES;                             // N
    int* csr_src = fill + NNODES;                             // E
    int* bsum    = csr_src + NEDGES;                          // NBLK
    int* boff    = bsum + NBLK;                               // NBLK

    const unsigned short* BTin    = BTpool;
    const unsigned short* BTqkvm0 = BTpool + 16384;
    const unsigned short* BTqkvm1 = BTpool + 74752;
    const unsigned short* BTo0    = BTpool + 133120;
    const unsigned short* BTo1    = BTpool + 165888;
    const unsigned short* BTout   = BTpool + 198656;

    // ---- prep: memset, then fused pack+convert+hist, then scan+scatter ----
    hipMemsetAsync(degi, 0, 2 * NNODES * sizeof(int), stream);  // degi + fill
    prep_kernel<<<cdiv(CONV_TOTAL, 256), 256, 0, stream>>>(
        x, ei, w_in, w_out, Wq, Wk, Wv, Wm, Wg, Wo,
        BTpool, (unsigned int*)xb, degi);
    scan_blk_kernel<<<NBLK, 256, 0, stream>>>(degi, rowptr, bsum);
    scan_top_kernel<<<1, 256, 0, stream>>>(bsum, boff, rowptr);
    scan_add_kernel<<<NBLK, 256, 0, stream>>>(rowptr, boff);
    scatter_kernel<<<cdiv(NEDGES, 256), 256, 0, stream>>>(ei, rowptr, fill, csr_src);

    const dim3 gM(1, cdiv(NNODES, 128));   // 391 blocks (round-11 best)

    // h0 = x @ w_in  -> feat0[.,456..583]
    gemm_1p<4, 0><<<gM, 256, 0, stream>>>(
        xb, 128, 128, nullptr, 0, 0, BTin,
        feat0, FSTR, OFF_H, NNODES, 128);

    unsigned short* featA = feat0;
    unsigned short* featB = feat1;
    for (int L = 0; L < 2; ++L) {
        const unsigned short* btq = L ? BTqkvm1 : BTqkvm0;
        const unsigned short* bto = L ? BTo1 : BTo0;
        const float* wg = Wg + (size_t)L * 320 * 8;

        // [q|k|v|m|hg] = h @ [wq|wk|wv|wm|wgm]  -> feat[.,0..455]
        gemm_1p<4, 0><<<gM, 256, 0, stream>>>(
            featA + OFF_H, FSTR, 128, nullptr, 0, 0, btq,
            featA, FSTR, 0, NNODES, 456);

        fused_edge_kernel<<<cdiv(NNODES, 4), 256, 0, stream>>>(
            rowptr, csr_src, featA, wg, gatedb);

        // h' = leaky_relu([h | gated] @ wo) -> featB[.,456..583]
        gemm_1p<8, 1><<<gM, 256, 0, stream>>>(
            featA + OFF_H, FSTR, 128, gatedb, 128, 128, bto,
            featB, FSTR, OFF_H, NNODES, 128);

        unsigned short* t = featA; featA = featB; featB = t;
    }

    // classifier + fused log-softmax (featA holds final hidden state)
    gemm_cls_lsm<<<gM, 256, 0, stream>>>(
        featA + OFF_H, FSTR, BTout, out, NNODES);
}